// Round 1
// baseline (179.548 us; speedup 1.0000x reference)
//
#include <hip/hip_runtime.h>
#include <hip/hip_bf16.h>

// LSTM cell fused kernel for MI355X (gfx950).
// stacked = [x|prevh] @ [Wx;Wh] + bx  -> gates -> nexth, nextc
// Strategy: bf16 MFMA GEMM (tolerance is bf16-floor), gate-fused epilogue.
//
// ws layout: A_bf16 [8192][2048] (32MB) | Wt_bf16 [4096][2048] (16MB)

#define BATCH   8192
#define SDIM    1024
#define KDIM    2048   // INPUT_DIM + STATE_DIM
#define NDIM    4096   // 4 * SDIM

typedef __attribute__((ext_vector_type(8))) short s16x8;
typedef __attribute__((ext_vector_type(4))) float f32x4;

__device__ __forceinline__ void gload16(const void* g, void* l) {
    __builtin_amdgcn_global_load_lds((const __attribute__((address_space(1))) void*)g,
                                     (__attribute__((address_space(3))) void*)l,
                                     16, 0, 0);
}

__device__ __forceinline__ float fast_sigmoid(float x) {
    return 1.0f / (1.0f + __expf(-x));
}
__device__ __forceinline__ float fast_tanh(float v) {
    float a = fabsf(v);
    float e = __expf(-2.0f * a);
    float t = (1.0f - e) / (1.0f + e);
    return copysignf(t, v);
}

// ---------------- conversion: A = [x | prevh] -> bf16 [8192][2048] ----------
__global__ void convA(const float* __restrict__ x, const float* __restrict__ h,
                      __hip_bfloat16* __restrict__ A) {
    int t = blockIdx.x * blockDim.x + threadIdx.x;   // 2,097,152 threads
    int e = t << 3;                                  // 8 elems/thread
    int b = e >> 11;                                 // /2048
    int k = e & 2047;
    const float* src = (k < 1024) ? (x + (size_t)b * 1024 + k)
                                  : (h + (size_t)b * 1024 + (k - 1024));
    float4 v0 = *(const float4*)(src);
    float4 v1 = *(const float4*)(src + 4);
    union { __hip_bfloat16 b[8]; s16x8 v; } u;
    u.b[0] = __float2bfloat16(v0.x); u.b[1] = __float2bfloat16(v0.y);
    u.b[2] = __float2bfloat16(v0.z); u.b[3] = __float2bfloat16(v0.w);
    u.b[4] = __float2bfloat16(v1.x); u.b[5] = __float2bfloat16(v1.y);
    u.b[6] = __float2bfloat16(v1.z); u.b[7] = __float2bfloat16(v1.w);
    *(s16x8*)(A + e) = u.v;
}

// -------- conversion + transpose: Wt[n][k] = W[k][n] -> bf16 [4096][2048] ---
__global__ void convW(const float* __restrict__ Wx, const float* __restrict__ Wh,
                      __hip_bfloat16* __restrict__ Wt) {
    __shared__ float tile[32][33];
    int k0 = blockIdx.x * 32;   // 64 tiles
    int n0 = blockIdx.y * 32;   // 128 tiles
    int tx = threadIdx.x;       // 0..31
    int ty = threadIdx.y;       // 0..7
#pragma unroll
    for (int j = 0; j < 4; ++j) {
        int k = k0 + ty + j * 8;
        int n = n0 + tx;
        float v = (k < 1024) ? Wx[(size_t)k * 4096 + n]
                             : Wh[(size_t)(k - 1024) * 4096 + n];
        tile[ty + j * 8][tx] = v;
    }
    __syncthreads();
#pragma unroll
    for (int j = 0; j < 4; ++j) {
        int n = n0 + ty + j * 8;
        int k = k0 + tx;
        Wt[(size_t)n * 2048 + k] = __float2bfloat16(tile[tx][ty + j * 8]);
    }
}

// ---------------- fused GEMM + gates ----------------------------------------
// Block: 128 rows x 32 state cols (effective GEMM tile 128x128 over 4 gates).
// 4 waves in 2x2 grid: wr over rows (64 each), wc over states (16 each).
// Each wave: 4 m-frags x 4 gate-frags of 16x16x32 bf16 MFMA.
__global__ __launch_bounds__(256, 2) void lstm_gemm(
    const __hip_bfloat16* __restrict__ A,    // [8192][2048]
    const __hip_bfloat16* __restrict__ Wt,   // [4096][2048]
    const float* __restrict__ bx,            // [4096]
    const float* __restrict__ prevc,         // [8192][1024]
    float* __restrict__ outh,
    float* __restrict__ outc)
{
    __shared__ __align__(16) __hip_bfloat16 ldsA[128 * 64];
    __shared__ __align__(16) __hip_bfloat16 ldsB[128 * 64];

    const int tid  = threadIdx.x;
    const int lane = tid & 63;
    const int w    = tid >> 6;
    const int wr   = w >> 1;
    const int wc   = w & 1;
    const int m0   = blockIdx.x * 128;  // row-tile base
    const int s0   = blockIdx.y * 32;   // state-tile base

    f32x4 acc[4][4];  // [m_frag][gate]
#pragma unroll
    for (int m = 0; m < 4; ++m)
#pragma unroll
        for (int g = 0; g < 4; ++g)
            acc[m][g] = (f32x4)0.0f;

    // staging geometry: per chunk c, wave w -> LDS elems [c*2048 + w*512 + lane*8)
    // row = c*32 + w*8 + lane/8 ; k-offset = (lane&7)*8
    const int srow = lane >> 3;
    const int skof = (lane & 7) * 8;
    const __hip_bfloat16* Ag = A + (size_t)m0 * KDIM;

    for (int kt = 0; kt < KDIM; kt += 64) {
        // ---- stage A tile [128][64] ----
#pragma unroll
        for (int c = 0; c < 4; ++c) {
            int r = c * 32 + w * 8 + srow;
            gload16(Ag + (size_t)r * KDIM + kt + skof, &ldsA[c * 2048 + w * 512]);
        }
        // ---- stage B tile: gate-major [4][32][64] ----
#pragma unroll
        for (int c = 0; c < 4; ++c) {
            int gs   = c * 32 + w * 8 + srow;   // 0..127
            int gate = gs >> 5;
            int sof  = gs & 31;
            gload16(Wt + (size_t)(gate * 1024 + s0 + sof) * KDIM + kt + skof,
                    &ldsB[c * 2048 + w * 512]);
        }
        __syncthreads();   // drains vmcnt before barrier (compiler-inserted)

        // ---- fragments ----
        s16x8 af[4][2], bf[4][2];
#pragma unroll
        for (int m = 0; m < 4; ++m)
#pragma unroll
            for (int kf = 0; kf < 2; ++kf)
                af[m][kf] = *(const s16x8*)&ldsA[(wr * 64 + m * 16 + (lane & 15)) * 64
                                                 + kf * 32 + (lane >> 4) * 8];
#pragma unroll
        for (int g = 0; g < 4; ++g)
#pragma unroll
            for (int kf = 0; kf < 2; ++kf)
                bf[g][kf] = *(const s16x8*)&ldsB[(g * 32 + wc * 16 + (lane & 15)) * 64
                                                 + kf * 32 + (lane >> 4) * 8];
#pragma unroll
        for (int kf = 0; kf < 2; ++kf)
#pragma unroll
            for (int m = 0; m < 4; ++m)
#pragma unroll
                for (int g = 0; g < 4; ++g)
                    acc[m][g] = __builtin_amdgcn_mfma_f32_16x16x32_bf16(
                        af[m][kf], bf[g][kf], acc[m][g], 0, 0, 0);
        __syncthreads();
    }

    // ---- fused epilogue: all 4 gates are lane-local ----
    const int scol = s0 + wc * 16 + (lane & 15);
    const float b_i = bx[scol];
    const float b_f = bx[1024 + scol];
    const float b_o = bx[2048 + scol];
    const float b_g = bx[3072 + scol];
    const int rbase = m0 + wr * 64 + (lane >> 4) * 4;

#pragma unroll
    for (int m = 0; m < 4; ++m) {
#pragma unroll
        for (int q = 0; q < 4; ++q) {
            int row = rbase + m * 16 + q;
            float ib = acc[m][0][q] + b_i;
            float fb = acc[m][1][q] + b_f;
            float ob = acc[m][2][q] + b_o;
            float gb = acc[m][3][q] + b_g;
            float ig = fast_sigmoid(ib);
            float fg = fast_sigmoid(fb);
            float og = fast_sigmoid(ob);
            float gg = fast_tanh(gb);
            float pc = prevc[(size_t)row * SDIM + scol];
            float nc = pc * fg + gg * ig;
            float nh = fast_tanh(nc) * og;
            outh[(size_t)row * SDIM + scol] = nh;
            outc[(size_t)row * SDIM + scol] = nc;
        }
    }
}

extern "C" void kernel_launch(void* const* d_in, const int* in_sizes, int n_in,
                              void* d_out, int out_size, void* d_ws, size_t ws_size,
                              hipStream_t stream) {
    const float* x     = (const float*)d_in[0];
    const float* prevh = (const float*)d_in[1];
    const float* prevc = (const float*)d_in[2];
    const float* Wx    = (const float*)d_in[3];
    const float* bx    = (const float*)d_in[4];
    const float* Wh    = (const float*)d_in[5];

    __hip_bfloat16* Abf = (__hip_bfloat16*)d_ws;
    __hip_bfloat16* Wt  = Abf + (size_t)BATCH * KDIM;   // +32MB

    float* outh = (float*)d_out;
    float* outc = outh + (size_t)BATCH * SDIM;

    // A conversion: 8192*2048 / 8 per thread = 2,097,152 threads
    hipLaunchKernelGGL(convA, dim3(8192), dim3(256), 0, stream, x, prevh, Abf);
    // W transpose+convert: tiles (k=2048/32, n=4096/32)
    hipLaunchKernelGGL(convW, dim3(64, 128), dim3(32, 8), 0, stream, Wx, Wh, Wt);
    // fused GEMM: 64 row-tiles x 32 state-tiles
    hipLaunchKernelGGL(lstm_gemm, dim3(64, 32), dim3(256), 0, stream,
                       Abf, Wt, bx, prevc, outh, outc);
}

// Round 2
// 175.035 us; speedup vs baseline: 1.0258x; 1.0258x over previous
//
#include <hip/hip_runtime.h>
#include <hip/hip_bf16.h>

// LSTM cell fused kernel for MI355X (gfx950) — round 2.
// stacked = [x|prevh] @ [Wx;Wh] + bx  -> gates -> nexth, nextc
// GEMM: M=8192, N=4096 (4 gates x 1024 states), K=2048, bf16 MFMA.
//
// Round-2 structure: 256x256 tile, BK=32, 8 waves (2Mx4N), 4 LDS buffers
// (128 KiB), counted-vmcnt pipeline (stage t+2 while computing t, vmcnt(8),
// ONE raw s_barrier per K-tile — never drains to 0), T2 both-sides XOR
// swizzle, T5 setprio, T1 XCD swizzle.
// Gate fusion: Wt is pre-PERMUTED so block's 256 N-cols = 64 states x 4 gates
// in wave-local order: n' = (s>>4)*64 + gate*16 + (s&15). Each wave's 4
// n-frags are the 4 gates for its 16 states -> lane-local epilogue.
//
// ws layout: A_bf16 [8192][2048] (32MB) | Wt_bf16 [4096 permuted][2048] (16MB)

#define BATCH   8192
#define SDIM    1024
#define KDIM    2048
#define NT      64      // K-tiles of 32

typedef __attribute__((ext_vector_type(8))) short s16x8;
typedef __attribute__((ext_vector_type(4))) float f32x4;

__device__ __forceinline__ void gload16(const void* g, void* l) {
    __builtin_amdgcn_global_load_lds((const __attribute__((address_space(1))) void*)g,
                                     (__attribute__((address_space(3))) void*)l,
                                     16, 0, 0);
}

__device__ __forceinline__ float fast_sigmoid(float x) {
    return 1.0f / (1.0f + __expf(-x));
}
__device__ __forceinline__ float fast_tanh(float v) {
    float a = fabsf(v);
    float e = __expf(-2.0f * a);
    float t = (1.0f - e) / (1.0f + e);
    return copysignf(t, v);
}

// ---------------- conversion: A = [x | prevh] -> bf16 [8192][2048] ----------
__global__ void convA(const float* __restrict__ x, const float* __restrict__ h,
                      __hip_bfloat16* __restrict__ A) {
    int t = blockIdx.x * blockDim.x + threadIdx.x;
    int e = t << 3;
    int b = e >> 11;
    int k = e & 2047;
    const float* src = (k < 1024) ? (x + (size_t)b * 1024 + k)
                                  : (h + (size_t)b * 1024 + (k - 1024));
    float4 v0 = *(const float4*)(src);
    float4 v1 = *(const float4*)(src + 4);
    union { __hip_bfloat16 b[8]; s16x8 v; } u;
    u.b[0] = __float2bfloat16(v0.x); u.b[1] = __float2bfloat16(v0.y);
    u.b[2] = __float2bfloat16(v0.z); u.b[3] = __float2bfloat16(v0.w);
    u.b[4] = __float2bfloat16(v1.x); u.b[5] = __float2bfloat16(v1.y);
    u.b[6] = __float2bfloat16(v1.z); u.b[7] = __float2bfloat16(v1.w);
    *(s16x8*)(A + e) = u.v;
}

// ---- conversion + transpose + gate-permute: Wt[n'][k] = W[k][n] -----------
// n = gate*1024 + s  ->  n' = (s>>4)*64 + gate*16 + (s&15)
__global__ void convW(const float* __restrict__ Wx, const float* __restrict__ Wh,
                      __hip_bfloat16* __restrict__ Wt) {
    __shared__ float tile[32][33];
    int k0 = blockIdx.x * 32;
    int n0 = blockIdx.y * 32;
    int tx = threadIdx.x;
    int ty = threadIdx.y;
#pragma unroll
    for (int j = 0; j < 4; ++j) {
        int k = k0 + ty + j * 8;
        int n = n0 + tx;
        float v = (k < 1024) ? Wx[(size_t)k * 4096 + n]
                             : Wh[(size_t)(k - 1024) * 4096 + n];
        tile[ty + j * 8][tx] = v;
    }
    __syncthreads();
#pragma unroll
    for (int j = 0; j < 4; ++j) {
        int n = n0 + ty + j * 8;
        int k = k0 + tx;
        int np = ((n & 1023) >> 4) * 64 + (n >> 10) * 16 + (n & 15);
        Wt[(size_t)np * 2048 + k] = __float2bfloat16(tile[tx][ty + j * 8]);
    }
}

// ---------------- fused GEMM + gates (counted-vmcnt pipeline) ---------------
// Race-freedom argument (1 barrier/iter, 4 buffers):
//   All waves passing barrier(t) => all finished iter t-1 entirely.
//   Max skew: fast wave in iter t+1 pre-barrier (writes buf[(t+3)&3] via
//   STAGE) while slow wave reads buf[t&3] in iter t. (t+3)-(t)=3 mod 4 != 0.
//   STAGE(t+2) at iter t writes buf[(t-2)&3], last read in iter t-2, which
//   all waves completed before barrier(t-1). Safe.
__global__ __launch_bounds__(512, 2) void lstm_gemm(
    const __hip_bfloat16* __restrict__ A,    // [8192][2048]
    const __hip_bfloat16* __restrict__ Wt,   // [4096 perm][2048]
    const float* __restrict__ bx,            // [4096]
    const float* __restrict__ prevc,         // [8192][1024]
    float* __restrict__ outh,
    float* __restrict__ outc)
{
    // 4 buffers x (A[256][32] + B[256][32]) bf16 = 4 x 32KB = 128 KiB
    __shared__ __align__(16) __hip_bfloat16 lds[4 * 16384];

    const int tid  = threadIdx.x;
    const int lane = tid & 63;
    const int w    = tid >> 6;   // 0..7
    const int wr   = w >> 2;     // 0..1  (M half)
    const int wc   = w & 3;      // 0..3  (N quarter)

    // T1: bijective XCD swizzle (512 blocks, 512 % 8 == 0)
    const int bid = blockIdx.x;
    const int swz = (bid & 7) * 64 + (bid >> 3);
    const int m0  = (swz & 31) * 256;   // 32 M-tiles
    const int nt  = swz >> 5;           // 16 N-tiles
    const int n0  = nt * 256;           // Wt row base (permuted space)
    const int S0  = nt * 64;            // state base

    f32x4 acc[8][4];   // [m_frag][gate]
#pragma unroll
    for (int m = 0; m < 8; ++m)
#pragma unroll
        for (int g = 0; g < 4; ++g)
            acc[m][g] = (f32x4)0.0f;

    // ---- staging geometry (T2: inverse-swizzled global source, linear LDS) ----
    // linear dest byte o = r*8192 + tid*16; row = o>>6; swizzle flips byte
    // bits[5:4] by row bits[1:0]  =>  src col elems = ((lane&3)^((lane>>2)&3))*8
    const int srow = lane >> 2;                                // + w*16 + r*128
    const int scol = (((lane & 3) ^ ((lane >> 2) & 3)) << 3);  // elems
    const __hip_bfloat16* Ag = A  + (size_t)m0 * KDIM;
    const __hip_bfloat16* Bg = Wt + (size_t)n0 * KDIM;

    auto STAGE = [&](int t) {
        const int b  = (t & 3) * 16384;
        const int kt = t * 32;
#pragma unroll
        for (int r = 0; r < 2; ++r) {
            int row = r * 128 + w * 16 + srow;
            gload16(Ag + (size_t)row * KDIM + kt + scol,
                    &lds[b + r * 4096 + w * 512]);
        }
#pragma unroll
        for (int r = 0; r < 2; ++r) {
            int row = r * 128 + w * 16 + srow;
            gload16(Bg + (size_t)row * KDIM + kt + scol,
                    &lds[b + 8192 + r * 4096 + w * 512]);
        }
    };

    STAGE(0);
    STAGE(1);

    // ---- read-side swizzle: slot' = slot ^ (row&3); row&3 == lane&3 always ----
    const int sslot = (((lane >> 4) ^ (lane & 3)) << 4);  // byte offset of 16B slot
    const int arow  = wr * 128 + (lane & 15);             // + m*16
    const int brow  = wc * 64  + (lane & 15);             // + g*16

    for (int t = 0; t < NT; ++t) {
        if (t + 2 < NT) {
            STAGE(t + 2);
            asm volatile("s_waitcnt vmcnt(8)" ::: "memory");  // tile t complete
        } else if (t + 1 < NT) {
            asm volatile("s_waitcnt vmcnt(4)" ::: "memory");
        } else {
            asm volatile("s_waitcnt vmcnt(0)" ::: "memory");
        }
        __builtin_amdgcn_s_barrier();
        __builtin_amdgcn_sched_barrier(0);

        const char* base = (const char*)lds + (t & 3) * 32768;
        s16x8 af[8], bfr[4];
#pragma unroll
        for (int m = 0; m < 8; ++m)
            af[m] = *(const s16x8*)(base + (arow + m * 16) * 64 + sslot);
#pragma unroll
        for (int g = 0; g < 4; ++g)
            bfr[g] = *(const s16x8*)(base + 16384 + (brow + g * 16) * 64 + sslot);

        __builtin_amdgcn_s_setprio(1);
#pragma unroll
        for (int m = 0; m < 8; ++m)
#pragma unroll
            for (int g = 0; g < 4; ++g)
                acc[m][g] = __builtin_amdgcn_mfma_f32_16x16x32_bf16(
                    af[m], bfr[g], acc[m][g], 0, 0, 0);
        __builtin_amdgcn_s_setprio(0);
    }

    // ---- fused epilogue: 4 gates lane-local ----
    const int st  = S0 + wc * 16 + (lane & 15);   // state column
    const float b_i = bx[st];
    const float b_f = bx[1024 + st];
    const float b_o = bx[2048 + st];
    const float b_g = bx[3072 + st];
    const int rbase = m0 + wr * 128 + (lane >> 4) * 4;

#pragma unroll
    for (int m = 0; m < 8; ++m) {
#pragma unroll
        for (int q = 0; q < 4; ++q) {
            int row = rbase + m * 16 + q;
            float ib = acc[m][0][q] + b_i;
            float fb = acc[m][1][q] + b_f;
            float ob = acc[m][2][q] + b_o;
            float gb = acc[m][3][q] + b_g;
            float ig = fast_sigmoid(ib);
            float fg = fast_sigmoid(fb);
            float og = fast_sigmoid(ob);
            float gg = fast_tanh(gb);
            float pc = prevc[(size_t)row * SDIM + st];
            float nc = pc * fg + gg * ig;
            float nh = fast_tanh(nc) * og;
            outh[(size_t)row * SDIM + st] = nh;
            outc[(size_t)row * SDIM + st] = nc;
        }
    }
}

extern "C" void kernel_launch(void* const* d_in, const int* in_sizes, int n_in,
                              void* d_out, int out_size, void* d_ws, size_t ws_size,
                              hipStream_t stream) {
    const float* x     = (const float*)d_in[0];
    const float* prevh = (const float*)d_in[1];
    const float* prevc = (const float*)d_in[2];
    const float* Wx    = (const float*)d_in[3];
    const float* bx    = (const float*)d_in[4];
    const float* Wh    = (const float*)d_in[5];

    __hip_bfloat16* Abf = (__hip_bfloat16*)d_ws;
    __hip_bfloat16* Wt  = Abf + (size_t)BATCH * KDIM;   // +32MB

    float* outh = (float*)d_out;
    float* outc = outh + (size_t)BATCH * SDIM;

    hipLaunchKernelGGL(convA, dim3(8192), dim3(256), 0, stream, x, prevh, Abf);
    hipLaunchKernelGGL(convW, dim3(64, 128), dim3(32, 8), 0, stream, Wx, Wh, Wt);
    // 32 M-tiles x 16 N-tiles = 512 blocks
    hipLaunchKernelGGL(lstm_gemm, dim3(512), dim3(512), 0, stream,
                       Abf, Wt, bx, prevc, outh, outc);
}

// Round 3
// 160.706 us; speedup vs baseline: 1.1172x; 1.0892x over previous
//
#include <hip/hip_runtime.h>
#include <hip/hip_bf16.h>

// LSTM cell fused kernel for MI355X (gfx950) — round 3: m201-style 8-phase.
// stacked = [x|prevh] @ [Wx;Wh] + bx  -> gates -> nexth, nextc
// GEMM: M=8192, N=4096 (4 gates x 1024 states), K=2048, bf16 16x16x32 MFMA.
//
// Structure: 256x256 tile, BK=64, 8 waves (2M x 4N), per-wave 128x64.
// LDS 128 KiB: per operand a ring of 4 half-slots (16KB = 128 rows x 64 cols
// bf16); half H = 2*tile+p lives in slot H&3. Each wave reads ONLY its
// A-half (p=wr) and B-half (p=wc>>1).
//
// Per K-tile t, 4 phases; each = {ds_read frags; stage 1 half; barrier;
// lgkmcnt(0); setprio(1); 16 MFMA; setprio(0); barrier}:
//   P1: read A[m0-3]x2kf(8) + B[g0-1]x2kf(4); stage A0(t+1); MFMA m0-3 x g0-1
//   P2: read B[g2-3](4);                      stage A1(t+1); MFMA m0-3 x g2-3
//   P3: read A[m4-7](8);                      stage B0(t+2); MFMA m4-7 x g2-3
//   P4: (no reads);                           stage B1(t+2); MFMA m4-7 x g0-1
//       then s_waitcnt vmcnt(4) before trailing barrier.
// vmcnt derivation: per-thread issue order ... A0(t+1)@P1(t)[2] A1(t+1)@P2(t)[2]
// B0(t+2)@P3(t)[2] B1(t+2)@P4(t)[2]. vmcnt(4) at P4(t) => everything through
// A1(t+1) landed (B(t+1) issued even earlier) = exactly what P1(t+1) reads;
// 4 loads (B halves of t+2) stay in flight — never drains to 0.
// Ring safety: A0(t+1) overwrites A0(t-1)'s slot, last read P3(t-1), staged
// after P4(t-1) trailing barrier. B0(t+2) overwrites B0(t)'s slot, last read
// P2(t), staged at P3(t) after P2's trailing barrier. Safe.
//
// T2 swizzle (both-sides, rule 21): rows are 128B; logical col granule
// gl(bits[6:4]) stored at gl ^ (row&7). Staging: linear gload_lds dest +
// inverse-swizzled global source col. Reads: 16-lane groups spread over all
// 8 granules, 2-way aliasing = free.
//
// Gate fusion: Wt pre-permuted n' = (s>>4)*64 + gate*16 + (s&15) so each
// wave's 64 N-cols = 16 states x 4 gates -> epilogue lane-local.
//
// ws layout: A_bf16 [8192][2048] (32MB) | Wt_bf16 [4096 perm][2048] (16MB)

#define BATCH   8192
#define SDIM    1024
#define KDIM    2048
#define NT      32      // K-tiles of 64

typedef __attribute__((ext_vector_type(8))) short s16x8;
typedef __attribute__((ext_vector_type(4))) float f32x4;

__device__ __forceinline__ void gload16(const void* g, void* l) {
    __builtin_amdgcn_global_load_lds((const __attribute__((address_space(1))) void*)g,
                                     (__attribute__((address_space(3))) void*)l,
                                     16, 0, 0);
}

__device__ __forceinline__ float fast_sigmoid(float x) {
    return 1.0f / (1.0f + __expf(-x));
}
__device__ __forceinline__ float fast_tanh(float v) {
    float a = fabsf(v);
    float e = __expf(-2.0f * a);
    float t = (1.0f - e) / (1.0f + e);
    return copysignf(t, v);
}

// ---------------- conversion: A = [x | prevh] -> bf16 [8192][2048] ----------
__global__ void convA(const float* __restrict__ x, const float* __restrict__ h,
                      __hip_bfloat16* __restrict__ A) {
    int t = blockIdx.x * blockDim.x + threadIdx.x;
    int e = t << 3;
    int b = e >> 11;
    int k = e & 2047;
    const float* src = (k < 1024) ? (x + (size_t)b * 1024 + k)
                                  : (h + (size_t)b * 1024 + (k - 1024));
    float4 v0 = *(const float4*)(src);
    float4 v1 = *(const float4*)(src + 4);
    union { __hip_bfloat16 b[8]; s16x8 v; } u;
    u.b[0] = __float2bfloat16(v0.x); u.b[1] = __float2bfloat16(v0.y);
    u.b[2] = __float2bfloat16(v0.z); u.b[3] = __float2bfloat16(v0.w);
    u.b[4] = __float2bfloat16(v1.x); u.b[5] = __float2bfloat16(v1.y);
    u.b[6] = __float2bfloat16(v1.z); u.b[7] = __float2bfloat16(v1.w);
    *(s16x8*)(A + e) = u.v;
}

// ---- conversion + transpose + gate-permute: Wt[n'][k] = W[k][n] -----------
// n = gate*1024 + s  ->  n' = (s>>4)*64 + gate*16 + (s&15)
__global__ void convW(const float* __restrict__ Wx, const float* __restrict__ Wh,
                      __hip_bfloat16* __restrict__ Wt) {
    __shared__ float tile[32][33];
    int k0 = blockIdx.x * 32;
    int n0 = blockIdx.y * 32;
    int tx = threadIdx.x;
    int ty = threadIdx.y;
#pragma unroll
    for (int j = 0; j < 4; ++j) {
        int k = k0 + ty + j * 8;
        int n = n0 + tx;
        float v = (k < 1024) ? Wx[(size_t)k * 4096 + n]
                             : Wh[(size_t)(k - 1024) * 4096 + n];
        tile[ty + j * 8][tx] = v;
    }
    __syncthreads();
#pragma unroll
    for (int j = 0; j < 4; ++j) {
        int n = n0 + ty + j * 8;
        int k = k0 + tx;
        int np = ((n & 1023) >> 4) * 64 + (n >> 10) * 16 + (n & 15);
        Wt[(size_t)np * 2048 + k] = __float2bfloat16(tile[tx][ty + j * 8]);
    }
}

// ---------------- fused GEMM + gates (8-phase schedule) ---------------------
__global__ __launch_bounds__(512, 2) void lstm_gemm(
    const __hip_bfloat16* __restrict__ A,    // [8192][2048]
    const __hip_bfloat16* __restrict__ Wt,   // [4096 perm][2048]
    const float* __restrict__ bx,            // [4096]
    const float* __restrict__ prevc,         // [8192][1024]
    float* __restrict__ outh,
    float* __restrict__ outc)
{
    // A: slots 0..3 at [0, 64K); B: slots at [64K, 128K). Slot = 16KB.
    __shared__ __align__(16) char lds[131072];

    const int tid  = threadIdx.x;
    const int lane = tid & 63;
    const int w    = tid >> 6;   // 0..7
    const int wr   = w >> 2;     // 0..1  A-half
    const int wc   = w & 3;      // 0..3  N quarter; B-half = wc>>1
    const int l15  = lane & 15;

    // XCD chunking: 8 chunks of (8 Mtiles x 8 Ntiles); first-resident 32
    // blocks per XCD form an 8M x 4N panel (A 8MB + B 4MB working set).
    const int bid = blockIdx.x;
    const int xcd = bid & 7, j = bid >> 3;
    const int mt = (xcd >> 1) * 8 + (j & 7);     // 0..31
    const int nt = (xcd & 1) * 8 + (j >> 3);     // 0..15
    const int m0 = mt * 256, n0 = nt * 256, S0 = nt * 64;

    // ---- staging: linear dest, inverse-swizzled source (rule 21) ----
    // dest row r = round*64 + w*8 + (lane>>3); dest granule = lane&7;
    // logical source granule = (lane&7) ^ (r&7), r&7 == lane>>3.
    const int scol = ((lane & 7) ^ (lane >> 3)) << 3;   // elems
    const __hip_bfloat16* Ag = A  + (size_t)m0 * KDIM;
    const __hip_bfloat16* Bg = Wt + (size_t)n0 * KDIM;

    auto SA = [&](int tt, int p) {
        char* dst = lds + (2 * (tt & 1) + p) * 16384 + w * 1024;
        const __hip_bfloat16* src =
            Ag + (size_t)(p * 128 + w * 8 + (lane >> 3)) * KDIM + tt * 64 + scol;
        gload16(src, dst);
        gload16(src + (size_t)64 * KDIM, dst + 8192);
    };
    auto SB = [&](int tt, int p) {
        char* dst = lds + 65536 + (2 * (tt & 1) + p) * 16384 + w * 1024;
        const __hip_bfloat16* src =
            Bg + (size_t)(p * 128 + w * 8 + (lane >> 3)) * KDIM + tt * 64 + scol;
        gload16(src, dst);
        gload16(src + (size_t)64 * KDIM, dst + 8192);
    };

    f32x4 acc[8][4];
#pragma unroll
    for (int m = 0; m < 8; ++m)
#pragma unroll
        for (int g = 0; g < 4; ++g)
            acc[m][g] = (f32x4)0.0f;

    // prologue: tile0 halves after B(0); then B(1) -> 12 loads, keep 4 in flight
    SB(0, 0); SB(0, 1); SA(0, 0); SA(0, 1); SB(1, 0); SB(1, 1);
    asm volatile("s_waitcnt vmcnt(4)" ::: "memory");
    __builtin_amdgcn_s_barrier();

    // read-side swizzle: granule' = (kf*4 + (lane>>4)) ^ (lane&7), bytes<<4
    const int swz0 = (((lane >> 4))     ^ (lane & 7)) << 4;
    const int swz1 = (((lane >> 4) | 4) ^ (lane & 7)) << 4;
    const int brow = (wc & 1) * 64;

    s16x8 af[4][2], bf[4][2];

#define PH_SYNC()                                           \
    __builtin_amdgcn_s_barrier();                           \
    asm volatile("s_waitcnt lgkmcnt(0)" ::: "memory");      \
    __builtin_amdgcn_sched_barrier(0);                      \
    __builtin_amdgcn_s_setprio(1);

#define PH_END()                                            \
    __builtin_amdgcn_s_setprio(0);                          \
    __builtin_amdgcn_s_barrier();

    for (int t = 0; t < NT; ++t) {
        const char* as = lds + (2 * (t & 1) + wr) * 16384;
        const char* bs = lds + 65536 + (2 * (t & 1) + (wc >> 1)) * 16384;

        // ---------------- P1: A[m0-3], B[g0-1]; stage A0(t+1) --------------
#pragma unroll
        for (int m = 0; m < 4; ++m) {
            af[m][0] = *(const s16x8*)(as + (m * 16 + l15) * 128 + swz0);
            af[m][1] = *(const s16x8*)(as + (m * 16 + l15) * 128 + swz1);
        }
#pragma unroll
        for (int g = 0; g < 2; ++g) {
            bf[g][0] = *(const s16x8*)(bs + (brow + g * 16 + l15) * 128 + swz0);
            bf[g][1] = *(const s16x8*)(bs + (brow + g * 16 + l15) * 128 + swz1);
        }
        if (t + 1 < NT) SA(t + 1, 0);
        PH_SYNC();
#pragma unroll
        for (int m = 0; m < 4; ++m)
#pragma unroll
            for (int g = 0; g < 2; ++g) {
                acc[m][g] = __builtin_amdgcn_mfma_f32_16x16x32_bf16(af[m][0], bf[g][0], acc[m][g], 0, 0, 0);
                acc[m][g] = __builtin_amdgcn_mfma_f32_16x16x32_bf16(af[m][1], bf[g][1], acc[m][g], 0, 0, 0);
            }
        PH_END();

        // ---------------- P2: B[g2-3]; stage A1(t+1) -----------------------
#pragma unroll
        for (int g = 2; g < 4; ++g) {
            bf[g][0] = *(const s16x8*)(bs + (brow + g * 16 + l15) * 128 + swz0);
            bf[g][1] = *(const s16x8*)(bs + (brow + g * 16 + l15) * 128 + swz1);
        }
        if (t + 1 < NT) SA(t + 1, 1);
        PH_SYNC();
#pragma unroll
        for (int m = 0; m < 4; ++m)
#pragma unroll
            for (int g = 2; g < 4; ++g) {
                acc[m][g] = __builtin_amdgcn_mfma_f32_16x16x32_bf16(af[m][0], bf[g][0], acc[m][g], 0, 0, 0);
                acc[m][g] = __builtin_amdgcn_mfma_f32_16x16x32_bf16(af[m][1], bf[g][1], acc[m][g], 0, 0, 0);
            }
        PH_END();

        // ---------------- P3: A[m4-7]; stage B0(t+2) -----------------------
#pragma unroll
        for (int m = 0; m < 4; ++m) {
            af[m][0] = *(const s16x8*)(as + ((m + 4) * 16 + l15) * 128 + swz0);
            af[m][1] = *(const s16x8*)(as + ((m + 4) * 16 + l15) * 128 + swz1);
        }
        if (t + 2 < NT) SB(t + 2, 0);
        PH_SYNC();
#pragma unroll
        for (int m = 0; m < 4; ++m)
#pragma unroll
            for (int g = 2; g < 4; ++g) {
                acc[m + 4][g] = __builtin_amdgcn_mfma_f32_16x16x32_bf16(af[m][0], bf[g][0], acc[m + 4][g], 0, 0, 0);
                acc[m + 4][g] = __builtin_amdgcn_mfma_f32_16x16x32_bf16(af[m][1], bf[g][1], acc[m + 4][g], 0, 0, 0);
            }
        PH_END();

        // ---------------- P4: stage B1(t+2); counted vmcnt -----------------
        if (t + 2 < NT) SB(t + 2, 1);
        __builtin_amdgcn_s_barrier();
        __builtin_amdgcn_s_setprio(1);
#pragma unroll
        for (int m = 0; m < 4; ++m)
#pragma unroll
            for (int g = 0; g < 2; ++g) {
                acc[m + 4][g] = __builtin_amdgcn_mfma_f32_16x16x32_bf16(af[m][0], bf[g][0], acc[m + 4][g], 0, 0, 0);
                acc[m + 4][g] = __builtin_amdgcn_mfma_f32_16x16x32_bf16(af[m][1], bf[g][1], acc[m + 4][g], 0, 0, 0);
            }
        __builtin_amdgcn_s_setprio(0);
        if (t + 2 < NT) {
            asm volatile("s_waitcnt vmcnt(4)" ::: "memory");
        } else {
            asm volatile("s_waitcnt vmcnt(0)" ::: "memory");
        }
        __builtin_amdgcn_s_barrier();
    }
#undef PH_SYNC
#undef PH_END

    // ---- fused epilogue: 4 gates lane-local ----
    const int st  = S0 + wc * 16 + l15;
    const float b_i = bx[st];
    const float b_f = bx[1024 + st];
    const float b_o = bx[2048 + st];
    const float b_g = bx[3072 + st];
    const int rbase = m0 + wr * 128 + (lane >> 4) * 4;

#pragma unroll
    for (int m = 0; m < 8; ++m) {
#pragma unroll
        for (int q = 0; q < 4; ++q) {
            int row = rbase + m * 16 + q;
            float ib = acc[m][0][q] + b_i;
            float fb = acc[m][1][q] + b_f;
            float ob = acc[m][2][q] + b_o;
            float gb = acc[m][3][q] + b_g;
            float ig = fast_sigmoid(ib);
            float fg = fast_sigmoid(fb);
            float og = fast_sigmoid(ob);
            float gg = fast_tanh(gb);
            float pc = prevc[(size_t)row * SDIM + st];
            float nc = pc * fg + gg * ig;
            float nh = fast_tanh(nc) * og;
            outh[(size_t)row * SDIM + st] = nh;
            outc[(size_t)row * SDIM + st] = nc;
        }
    }
}

extern "C" void kernel_launch(void* const* d_in, const int* in_sizes, int n_in,
                              void* d_out, int out_size, void* d_ws, size_t ws_size,
                              hipStream_t stream) {
    const float* x     = (const float*)d_in[0];
    const float* prevh = (const float*)d_in[1];
    const float* prevc = (const float*)d_in[2];
    const float* Wx    = (const float*)d_in[3];
    const float* bx    = (const float*)d_in[4];
    const float* Wh    = (const float*)d_in[5];

    __hip_bfloat16* Abf = (__hip_bfloat16*)d_ws;
    __hip_bfloat16* Wt  = Abf + (size_t)BATCH * KDIM;   // +32MB

    float* outh = (float*)d_out;
    float* outc = outh + (size_t)BATCH * SDIM;

    hipLaunchKernelGGL(convA, dim3(8192), dim3(256), 0, stream, x, prevh, Abf);
    hipLaunchKernelGGL(convW, dim3(64, 128), dim3(32, 8), 0, stream, Wx, Wh, Wt);
    // 32 M-tiles x 16 N-tiles = 512 blocks
    hipLaunchKernelGGL(lstm_gemm, dim3(512), dim3(512), 0, stream,
                       Abf, Wt, bx, prevc, outh, outc);
}

// Round 4
// 156.357 us; speedup vs baseline: 1.1483x; 1.0278x over previous
//
#include <hip/hip_runtime.h>
#include <hip/hip_bf16.h>

// LSTM cell fused kernel for MI355X (gfx950) — round 4: 2-barrier tile,
// compiler-counted lgkm waits, kf-outer MFMA.
// stacked = [x|prevh] @ [Wx;Wh] + bx  -> gates -> nexth, nextc
// GEMM: M=8192, N=4096 (4 gates x 1024 states), K=2048, bf16 16x16x32 MFMA.
//
// Geometry (unchanged): 256x256 tile, BK=64, 8 waves (2M x 4N), per-wave
// 128x64. LDS 128 KiB: A ring 4 half-slots [0,64K), B ring 4 half-slots
// [64K,128K); half (tile t, p) lives at slot 2*(t&1)+p.
//
// Per-tile schedule (2 barriers):
//   region 1 (after tile-start barrier):
//     issue ds_reads: bf[g0-3]x2kf (8), af[m0-3]x2kf (8)  [A-lo]
//     issue SA(t+1,0), SA(t+1,1)   (4 gloads, A one tile ahead)
//     32 MFMA kf-outer: m0-3 x g0-3        (compiler inserts counted lgkm)
//   mid-barrier  (=> all waves' B(t) reads retired)
//   region 2:
//     issue ds_reads: af[m4-7]x2kf (8)  [A-hi, reuses af regs]
//     issue SB(t+2,0), SB(t+2,1)   (4 gloads; B(t+2) slot == B(t) slot,
//                                   safe only after mid-barrier)
//     32 MFMA kf-outer: m4-7 x g0-3
//     s_waitcnt vmcnt(4)  -> queue at this point (oldest first):
//        SB(t+1)[4, issued last tile], SA(t+1)[4], SB(t+2)[4]
//        vmcnt(4) confirms SB(t+1)+SA(t+1) == everything tile t+1 reads;
//        SB(t+2) stays in flight. Never drains to 0 mid-loop.
//   end-barrier
// Read-after-write: tile-t reads covered by end-of-(t-1) vmcnt(4)+barrier.
// Write-after-read: SA(t+1) writes opposite parity of A(t) being read; its
// old contents (A(t-1)) fully read before tile-start barrier. SB(t+2) gated
// by mid-barrier. Safe.
//
// T2 swizzle both-sides (rule 21), XCD chunking, gate-permuted Wt, lane-local
// epilogue: unchanged from round 3 (bank conflicts measured 0).
//
// ws layout: A_bf16 [8192][2048] (32MB) | Wt_bf16 [4096 perm][2048] (16MB)

#define BATCH   8192
#define SDIM    1024
#define KDIM    2048
#define NT      32      // K-tiles of 64

typedef __attribute__((ext_vector_type(8))) short s16x8;
typedef __attribute__((ext_vector_type(4))) float f32x4;

__device__ __forceinline__ void gload16(const void* g, void* l) {
    __builtin_amdgcn_global_load_lds((const __attribute__((address_space(1))) void*)g,
                                     (__attribute__((address_space(3))) void*)l,
                                     16, 0, 0);
}

__device__ __forceinline__ float fast_sigmoid(float x) {
    return 1.0f / (1.0f + __expf(-x));
}
__device__ __forceinline__ float fast_tanh(float v) {
    float a = fabsf(v);
    float e = __expf(-2.0f * a);
    float t = (1.0f - e) / (1.0f + e);
    return copysignf(t, v);
}

// ---------------- conversion: A = [x | prevh] -> bf16 [8192][2048] ----------
__global__ void convA(const float* __restrict__ x, const float* __restrict__ h,
                      __hip_bfloat16* __restrict__ A) {
    int t = blockIdx.x * blockDim.x + threadIdx.x;
    int e = t << 3;
    int b = e >> 11;
    int k = e & 2047;
    const float* src = (k < 1024) ? (x + (size_t)b * 1024 + k)
                                  : (h + (size_t)b * 1024 + (k - 1024));
    float4 v0 = *(const float4*)(src);
    float4 v1 = *(const float4*)(src + 4);
    union { __hip_bfloat16 b[8]; s16x8 v; } u;
    u.b[0] = __float2bfloat16(v0.x); u.b[1] = __float2bfloat16(v0.y);
    u.b[2] = __float2bfloat16(v0.z); u.b[3] = __float2bfloat16(v0.w);
    u.b[4] = __float2bfloat16(v1.x); u.b[5] = __float2bfloat16(v1.y);
    u.b[6] = __float2bfloat16(v1.z); u.b[7] = __float2bfloat16(v1.w);
    *(s16x8*)(A + e) = u.v;
}

// ---- conversion + transpose + gate-permute: Wt[n'][k] = W[k][n] -----------
// n = gate*1024 + s  ->  n' = (s>>4)*64 + gate*16 + (s&15)
__global__ void convW(const float* __restrict__ Wx, const float* __restrict__ Wh,
                      __hip_bfloat16* __restrict__ Wt) {
    __shared__ float tile[32][33];
    int k0 = blockIdx.x * 32;
    int n0 = blockIdx.y * 32;
    int tx = threadIdx.x;
    int ty = threadIdx.y;
#pragma unroll
    for (int j = 0; j < 4; ++j) {
        int k = k0 + ty + j * 8;
        int n = n0 + tx;
        float v = (k < 1024) ? Wx[(size_t)k * 4096 + n]
                             : Wh[(size_t)(k - 1024) * 4096 + n];
        tile[ty + j * 8][tx] = v;
    }
    __syncthreads();
#pragma unroll
    for (int j = 0; j < 4; ++j) {
        int n = n0 + ty + j * 8;
        int k = k0 + tx;
        int np = ((n & 1023) >> 4) * 64 + (n >> 10) * 16 + (n & 15);
        Wt[(size_t)np * 2048 + k] = __float2bfloat16(tile[tx][ty + j * 8]);
    }
}

// ---------------- fused GEMM + gates ----------------------------------------
__global__ __launch_bounds__(512, 2) void lstm_gemm(
    const __hip_bfloat16* __restrict__ A,    // [8192][2048]
    const __hip_bfloat16* __restrict__ Wt,   // [4096 perm][2048]
    const float* __restrict__ bx,            // [4096]
    const float* __restrict__ prevc,         // [8192][1024]
    float* __restrict__ outh,
    float* __restrict__ outc)
{
    __shared__ __align__(16) char lds[131072];

    const int tid  = threadIdx.x;
    const int lane = tid & 63;
    const int w    = tid >> 6;   // 0..7
    const int wr   = w >> 2;     // 0..1  A-half
    const int wc   = w & 3;      // 0..3  N quarter; B-half = wc>>1
    const int l15  = lane & 15;

    // XCD chunking: 8 chunks of (8 Mtiles x 8 Ntiles); resident 32 blocks
    // per XCD form an 8M x 4N panel.
    const int bid = blockIdx.x;
    const int xcd = bid & 7, j = bid >> 3;
    const int mt = (xcd >> 1) * 8 + (j & 7);     // 0..31
    const int nt = (xcd & 1) * 8 + (j >> 3);     // 0..15
    const int m0 = mt * 256, n0 = nt * 256, S0 = nt * 64;

    // staging: linear gload_lds dest, inverse-swizzled global source.
    const int scol = ((lane & 7) ^ (lane >> 3)) << 3;   // elems
    const __hip_bfloat16* Ag = A  + (size_t)m0 * KDIM;
    const __hip_bfloat16* Bg = Wt + (size_t)n0 * KDIM;

    auto SA = [&](int tt, int p) {
        char* dst = lds + (2 * (tt & 1) + p) * 16384 + w * 1024;
        const __hip_bfloat16* src =
            Ag + (size_t)(p * 128 + w * 8 + (lane >> 3)) * KDIM + tt * 64 + scol;
        gload16(src, dst);
        gload16(src + (size_t)64 * KDIM, dst + 8192);
    };
    auto SB = [&](int tt, int p) {
        char* dst = lds + 65536 + (2 * (tt & 1) + p) * 16384 + w * 1024;
        const __hip_bfloat16* src =
            Bg + (size_t)(p * 128 + w * 8 + (lane >> 3)) * KDIM + tt * 64 + scol;
        gload16(src, dst);
        gload16(src + (size_t)64 * KDIM, dst + 8192);
    };

    f32x4 acc[8][4];
#pragma unroll
    for (int m = 0; m < 8; ++m)
#pragma unroll
        for (int g = 0; g < 4; ++g)
            acc[m][g] = (f32x4)0.0f;

    // prologue: B(0),A(0),B(1) = 12 loads; vmcnt(4) leaves SB(1) in flight.
    SB(0, 0); SB(0, 1); SA(0, 0); SA(0, 1); SB(1, 0); SB(1, 1);
    asm volatile("s_waitcnt vmcnt(4)" ::: "memory");
    __builtin_amdgcn_s_barrier();
    __builtin_amdgcn_sched_barrier(0);

    // read-side swizzle: granule' = (kf*4 + (lane>>4)) ^ (lane&7), bytes<<4
    const int swz0 = (((lane >> 4))     ^ (lane & 7)) << 4;
    const int swz1 = (((lane >> 4) | 4) ^ (lane & 7)) << 4;
    const int brow = (wc & 1) * 64;

    s16x8 af[4][2], bf[4][2];

    for (int t = 0; t < NT; ++t) {
        const char* as = lds + (2 * (t & 1) + wr) * 16384;
        const char* bs = lds + 65536 + (2 * (t & 1) + (wc >> 1)) * 16384;

        // ---- region 1: B reads, A-lo reads, SA(t+1); MFMA m0-3 x g0-3 ----
#pragma unroll
        for (int g = 0; g < 4; ++g) {
            bf[g][0] = *(const s16x8*)(bs + (brow + g * 16 + l15) * 128 + swz0);
            bf[g][1] = *(const s16x8*)(bs + (brow + g * 16 + l15) * 128 + swz1);
        }
#pragma unroll
        for (int m = 0; m < 4; ++m) {
            af[m][0] = *(const s16x8*)(as + (m * 16 + l15) * 128 + swz0);
            af[m][1] = *(const s16x8*)(as + (m * 16 + l15) * 128 + swz1);
        }
        if (t + 1 < NT) { SA(t + 1, 0); SA(t + 1, 1); }

        __builtin_amdgcn_s_setprio(1);
#pragma unroll
        for (int kf = 0; kf < 2; ++kf)      // kf outer: 16 indep accs between deps
#pragma unroll
            for (int m = 0; m < 4; ++m)
#pragma unroll
                for (int g = 0; g < 4; ++g)
                    acc[m][g] = __builtin_amdgcn_mfma_f32_16x16x32_bf16(
                        af[m][kf], bf[g][kf], acc[m][g], 0, 0, 0);
        __builtin_amdgcn_s_setprio(0);

        __builtin_amdgcn_sched_barrier(0);
        __builtin_amdgcn_s_barrier();        // mid: all B(t) reads retired
        __builtin_amdgcn_sched_barrier(0);

        // ---- region 2: A-hi reads (reuse af), SB(t+2); MFMA m4-7 x g0-3 ----
#pragma unroll
        for (int m = 0; m < 4; ++m) {
            af[m][0] = *(const s16x8*)(as + ((m + 4) * 16 + l15) * 128 + swz0);
            af[m][1] = *(const s16x8*)(as + ((m + 4) * 16 + l15) * 128 + swz1);
        }
        if (t + 2 < NT) { SB(t + 2, 0); SB(t + 2, 1); }

        __builtin_amdgcn_s_setprio(1);
#pragma unroll
        for (int kf = 0; kf < 2; ++kf)
#pragma unroll
            for (int m = 0; m < 4; ++m)
#pragma unroll
                for (int g = 0; g < 4; ++g)
                    acc[m + 4][g] = __builtin_amdgcn_mfma_f32_16x16x32_bf16(
                        af[m][kf], bf[g][kf], acc[m + 4][g], 0, 0, 0);
        __builtin_amdgcn_s_setprio(0);

        __builtin_amdgcn_sched_barrier(0);
        if (t + 2 < NT) {
            asm volatile("s_waitcnt vmcnt(4)" ::: "memory");
        } else {
            asm volatile("s_waitcnt vmcnt(0)" ::: "memory");
        }
        __builtin_amdgcn_s_barrier();        // end: tile t+1 slots published
        __builtin_amdgcn_sched_barrier(0);
    }

    // ---- fused epilogue: 4 gates lane-local ----
    const int st  = S0 + wc * 16 + l15;
    const float b_i = bx[st];
    const float b_f = bx[1024 + st];
    const float b_o = bx[2048 + st];
    const float b_g = bx[3072 + st];
    const int rbase = m0 + wr * 128 + (lane >> 4) * 4;

#pragma unroll
    for (int m = 0; m < 8; ++m) {
#pragma unroll
        for (int q = 0; q < 4; ++q) {
            int row = rbase + m * 16 + q;
            float ib = acc[m][0][q] + b_i;
            float fb = acc[m][1][q] + b_f;
            float ob = acc[m][2][q] + b_o;
            float gb = acc[m][3][q] + b_g;
            float ig = fast_sigmoid(ib);
            float fg = fast_sigmoid(fb);
            float og = fast_sigmoid(ob);
            float gg = fast_tanh(gb);
            float pc = prevc[(size_t)row * SDIM + st];
            float nc = pc * fg + gg * ig;
            float nh = fast_tanh(nc) * og;
            outh[(size_t)row * SDIM + st] = nh;
            outc[(size_t)row * SDIM + st] = nc;
        }
    }
}

extern "C" void kernel_launch(void* const* d_in, const int* in_sizes, int n_in,
                              void* d_out, int out_size, void* d_ws, size_t ws_size,
                              hipStream_t stream) {
    const float* x     = (const float*)d_in[0];
    const float* prevh = (const float*)d_in[1];
    const float* prevc = (const float*)d_in[2];
    const float* Wx    = (const float*)d_in[3];
    const float* bx    = (const float*)d_in[4];
    const float* Wh    = (const float*)d_in[5];

    __hip_bfloat16* Abf = (__hip_bfloat16*)d_ws;
    __hip_bfloat16* Wt  = Abf + (size_t)BATCH * KDIM;   // +32MB

    float* outh = (float*)d_out;
    float* outc = outh + (size_t)BATCH * SDIM;

    hipLaunchKernelGGL(convA, dim3(8192), dim3(256), 0, stream, x, prevh, Abf);
    hipLaunchKernelGGL(convW, dim3(64, 128), dim3(32, 8), 0, stream, Wx, Wh, Wt);
    hipLaunchKernelGGL(lstm_gemm, dim3(512), dim3(512), 0, stream,
                       Abf, Wt, bx, prevc, outh, outc);
}